// Round 2
// baseline (394.980 us; speedup 1.0000x reference)
//
#include <hip/hip_runtime.h>
#include <hip/hip_bf16.h>
#include <cstdint>

#define BATCH   4096
#define IN_DIM  1024
#define OUT_DIM 1024
#define NEXP    16

typedef __bf16 bf16;
typedef __attribute__((ext_vector_type(8))) __bf16 bf16x8;
typedef __attribute__((ext_vector_type(4))) float  f32x4;

#define AS1 __attribute__((address_space(1)))
#define AS3 __attribute__((address_space(3)))

__device__ __forceinline__ void gld_lds16(const bf16* g, bf16* l) {
    __builtin_amdgcn_global_load_lds((const AS1 void*)g, (AS3 void*)l, 16, 0, 0);
}

// Counted wait (T4), immediate via "n" constraint. NO "memory" clobber —
// ordering is enforced by sched_barrier(0) at the region edges (the
// verified m201/8-phase idiom); a "memory" clobber here is what forced
// captured state to scratch in the previous version.
template <int N>
__device__ __forceinline__ void wait_vm() {
    asm volatile("s_waitcnt vmcnt(%0)" :: "n"(N));
}

// ---------------------------------------------------------------------------
// Merged conversion kernel (unchanged from previous round).
// Blocks [0,4096): weight fp32 -> fragment-ordered bf16 tiles via LDS
//   transpose (coalesced f32x4 row reads).
// Blocks [4096,4608): x fp32 -> 512 pre-tiled swizzled bf16 images.
// ---------------------------------------------------------------------------
__global__ __launch_bounds__(256) void convert_all(
        const float* __restrict__ x, const float* __restrict__ W,
        bf16* __restrict__ xt, bf16* __restrict__ wt) {
    __shared__ float Ls[64][65];       // pad 65: read phase is 2-way (free)
    int t = threadIdx.x;
    int bid = blockIdx.x;
    if (bid < 4096) {
        int nblk = bid >> 8, ne = (bid >> 4) & 15, ks = bid & 15;
        int kb = ne * 1024 + ks * 64;
        int n0 = nblk * 64;
#pragma unroll
        for (int r = 0; r < 4; r++) {
            int idx = r * 256 + t;             // 1024 f32x4 = 64x64 tile
            int row = idx >> 4, c4 = (idx & 15) * 4;
            f32x4 v = *(const f32x4*)(W + (size_t)(kb + row) * OUT_DIM + n0 + c4);
#pragma unroll
            for (int j = 0; j < 4; j++) Ls[row][c4 + j] = v[j];
        }
        __syncthreads();
#pragma unroll
        for (int r = 0; r < 2; r++) {
            int c = r * 256 + t;               // 0..511
            int sub = c >> 6, l = c & 63;
            int lr = l & 15, lq = l >> 4;
            int kk = sub >> 2, wn = (sub >> 1) & 1, nt = sub & 1;
            int krow = kk * 32 + lq * 8;
            int col = wn * 32 + nt * 16 + lr;
            bf16x8 v;
#pragma unroll
            for (int j = 0; j < 8; j++) v[j] = (bf16)Ls[krow + j][col];
            *(bf16x8*)(wt + (size_t)bid * 4096 + c * 8) = v;
        }
    } else {
        int tile = bid - 4096;                 // 512
        int mblk = tile >> 4, ks = tile & 15;
#pragma unroll
        for (int r = 0; r < 4; r++) {
            int q = r * 256 + t;
            int m_loc = q >> 3, sc = q & 7;
            int cc = sc ^ (m_loc & 7);
            const float* src = x + (size_t)(mblk * 128 + m_loc) * IN_DIM + ks * 64 + cc * 8;
            f32x4 a = *(const f32x4*)src;
            f32x4 b = *(const f32x4*)(src + 4);
            bf16x8 v;
#pragma unroll
            for (int j = 0; j < 4; j++) { v[j] = (bf16)a[j]; v[4 + j] = (bf16)b[j]; }
            *(bf16x8*)(xt + (size_t)tile * 8192 + q * 8) = v;
        }
    }
}

// ---------------------------------------------------------------------------
// GEMM, counted-vmcnt pipeline (T3+T4) + setprio (T5), MACRO-expanded step
// (no lambda, nothing address-taken -> no scratch).
// Step g = ks*16 + ne (256). B(g) in Bs[g&3] (4 bufs, prefetch distance 2),
// A(ks) in As[ks&1] (2 bufs, prefetched at ne==13). One raw s_barrier per
// step; vmcnt never drained to 0 in the main loop.
//   vmcnt arithmetic (in-order retirement): steady {B(g+1),B(g+2)} = 4;
//   ne 13/14/15 of ks<15 carry the 4 A loads -> 8; ks==15 tail 4,...,4,2,0.
//   WAR safety: B(g+2) overwrites the buffer last read at step g-2; every
//   wave passed barrier g-1 (after compute g-2) before any wave issues at g.
// Block 128m x 64n, 4 waves (2x2), wave tile 64x32, mfma 16x16x32 bf16.
// LDS 73.9 KB -> 2 blocks/CU (grid is exactly 2/CU anyway).
// ---------------------------------------------------------------------------
#define STEP(NE, DO_B, DO_A, VM) do {                                          \
    if (DO_B) {                                                                \
        const bf16* bn_ = bbase +                                              \
            (size_t)((((NE) + 2) & 15) * 16 + ks + (((NE) + 2) >> 4)) * 4096   \
            + t * 8;                                                           \
        bf16* bd_ = &Bs[((NE) + 2) & 3][t * 8];                                \
        gld_lds16(bn_, bd_);                                                   \
        gld_lds16(bn_ + 2048, bd_ + 2048);                                     \
    }                                                                          \
    if (DO_A) {                                                                \
        const bf16* an_ = abase + (size_t)(ks + 1) * 8192 + t * 8;             \
        bf16* ad_ = &As[(ks + 1) & 1][t * 8];                                  \
        gld_lds16(an_,        ad_);                                            \
        gld_lds16(an_ + 2048, ad_ + 2048);                                     \
        gld_lds16(an_ + 4096, ad_ + 4096);                                     \
        gld_lds16(an_ + 6144, ad_ + 6144);                                     \
    }                                                                          \
    __builtin_amdgcn_sched_barrier(0);                                         \
    wait_vm<VM>();                                                             \
    __builtin_amdgcn_sched_barrier(0);                                         \
    __builtin_amdgcn_s_barrier();                                              \
    __builtin_amdgcn_sched_barrier(0);                                         \
    if ((NE) == 0) {                                                           \
        _Pragma("unroll")                                                      \
        for (int kk = 0; kk < 2; kk++)                                         \
            _Pragma("unroll")                                                  \
            for (int mt = 0; mt < 4; mt++)                                     \
                af[mt][kk] = *(const bf16x8*)                                  \
                    &As[ks & 1][mrow[mt] + ((kk * 4 + lq) ^ swz) * 8];         \
    }                                                                          \
    bf16x8 bfr_[2][2];                                                         \
    _Pragma("unroll")                                                          \
    for (int kk = 0; kk < 2; kk++)                                             \
        _Pragma("unroll")                                                      \
        for (int nt = 0; nt < 2; nt++)                                         \
            bfr_[kk][nt] = *(const bf16x8*)                                    \
                &Bs[(NE) & 3][((kk * 2 + wn) * 2 + nt) * 512 + lane * 8];      \
    f32x4 s_[4];                                                               \
    _Pragma("unroll")                                                          \
    for (int mt = 0; mt < 4; mt++)                                             \
        s_[mt] = *(const f32x4*)&cwT[(NE) * 132 + wm * 64 + mt * 16 + lq * 4]; \
    __builtin_amdgcn_s_setprio(1);                                             \
    _Pragma("unroll")                                                          \
    for (int mt = 0; mt < 4; mt++)                                             \
        _Pragma("unroll")                                                      \
        for (int nt = 0; nt < 2; nt++) {                                       \
            f32x4 p_ = __builtin_amdgcn_mfma_f32_16x16x32_bf16(                \
                af[mt][0], bfr_[0][nt], fz, 0, 0, 0);                          \
            p_ = __builtin_amdgcn_mfma_f32_16x16x32_bf16(                      \
                af[mt][1], bfr_[1][nt], p_, 0, 0, 0);                          \
            acc[mt][nt] += s_[mt] * p_;                                        \
        }                                                                      \
    __builtin_amdgcn_s_setprio(0);                                             \
} while (0)

__global__ __launch_bounds__(256, 2) void moe_gemm(
        const float* __restrict__ cw, const float* __restrict__ bias,
        const bf16* __restrict__ xt, const bf16* __restrict__ wt,
        float* __restrict__ out) {
    int nblk = blockIdx.x;                 // 16; bid%8 = nblk%8 -> same-nblk
    int mblk = blockIdx.y;                 // 32   blocks share an XCD L2 (B panel)
    int m0 = mblk * 128, n0 = nblk * 64;
    int t = threadIdx.x;
    int lane = t & 63, w = t >> 6;
    int wm = w >> 1, wn = w & 1;
    int lq = lane >> 4, lr = lane & 15;

    __shared__ bf16 As[2][128 * 64];       // 2 x 16 KB swizzled A images
    __shared__ bf16 Bs[4][64 * 64];        // 4 x 8 KB fragment-ordered B tiles
    __shared__ float cwT[16 * 132];        // cwT[ne][row], stride 132 (banks)

    // transpose cw panel into LDS once (drained by the one __syncthreads,
    // before any pipeline stage is in flight)
#pragma unroll
    for (int r = 0; r < 2; r++) {
        int q = r * 256 + t;               // 512 f32x4 = 2048 floats
        f32x4 v = *(const f32x4*)(cw + (size_t)m0 * NEXP + q * 4);
        int row = q >> 2, nb = (q & 3) * 4;
#pragma unroll
        for (int c2 = 0; c2 < 4; c2++) cwT[(nb + c2) * 132 + row] = v[c2];
    }
    __syncthreads();

    const bf16* abase = xt + (size_t)(mblk * 16) * 8192;
    const bf16* bbase = wt + (size_t)nblk * (16 * 16 * 4096);

    // prologue: issue A(0) [4], B(0) [2], B(1) [2] -> 8 in flight
    {
        const bf16* a0 = abase + t * 8;
#pragma unroll
        for (int r = 0; r < 4; r++) gld_lds16(a0 + r * 2048, &As[0][r * 2048 + t * 8]);
        const bf16* b0 = bbase + t * 8;                     // tile (ne=0,ks=0)
        gld_lds16(b0, &Bs[0][t * 8]);
        gld_lds16(b0 + 2048, &Bs[0][2048 + t * 8]);
        const bf16* b1 = bbase + (size_t)16 * 4096 + t * 8; // tile (ne=1,ks=0)
        gld_lds16(b1, &Bs[1][t * 8]);
        gld_lds16(b1 + 2048, &Bs[1][2048 + t * 8]);
    }

    const f32x4 fz = {0.f, 0.f, 0.f, 0.f};
    f32x4 acc[4][2];
#pragma unroll
    for (int mt = 0; mt < 4; mt++)
#pragma unroll
        for (int nt = 0; nt < 2; nt++) acc[mt][nt] = fz;

    int swz = lr & 7;
    int mrow[4];
#pragma unroll
    for (int mt = 0; mt < 4; mt++) mrow[mt] = (wm * 64 + mt * 16 + lr) * 64;

    bf16x8 af[4][2];                       // A frags, live across one ks

    for (int ks = 0; ks < 15; ks++) {
        STEP(0, 1, 0, 4);  STEP(1, 1, 0, 4);  STEP(2, 1, 0, 4);  STEP(3, 1, 0, 4);
        STEP(4, 1, 0, 4);  STEP(5, 1, 0, 4);  STEP(6, 1, 0, 4);  STEP(7, 1, 0, 4);
        STEP(8, 1, 0, 4);  STEP(9, 1, 0, 4);  STEP(10, 1, 0, 4); STEP(11, 1, 0, 4);
        STEP(12, 1, 0, 4); STEP(13, 1, 1, 8); STEP(14, 1, 0, 8); STEP(15, 1, 0, 8);
    }
    {   // peeled ks == 15: no A prefetch; B issue only while g+2 <= 255
        const int ks = 15;
        STEP(0, 1, 0, 4);  STEP(1, 1, 0, 4);  STEP(2, 1, 0, 4);  STEP(3, 1, 0, 4);
        STEP(4, 1, 0, 4);  STEP(5, 1, 0, 4);  STEP(6, 1, 0, 4);  STEP(7, 1, 0, 4);
        STEP(8, 1, 0, 4);  STEP(9, 1, 0, 4);  STEP(10, 1, 0, 4); STEP(11, 1, 0, 4);
        STEP(12, 1, 0, 4); STEP(13, 1, 0, 4); STEP(14, 0, 0, 2); STEP(15, 0, 0, 0);
    }

    // ---- bias: one MFMA k-step, operands loaded straight to registers ----
    {
        bf16x8 acw[4];
#pragma unroll
        for (int mt = 0; mt < 4; mt++) {
            bf16x8 v;
#pragma unroll
            for (int j = 0; j < 8; j++) v[j] = (bf16)0.f;
            if (lq < 2) {                  // k = lq*8+j in 0..15 real, else 0
                int row = m0 + wm * 64 + mt * 16 + lr;
                f32x4 a = *(const f32x4*)(cw + (size_t)row * NEXP + lq * 8);
                f32x4 b = *(const f32x4*)(cw + (size_t)row * NEXP + lq * 8 + 4);
#pragma unroll
                for (int j = 0; j < 4; j++) { v[j] = (bf16)a[j]; v[4 + j] = (bf16)b[j]; }
            }
            acw[mt] = v;
        }
        bf16x8 bb[2];
#pragma unroll
        for (int nt = 0; nt < 2; nt++) {
            bf16x8 v;
#pragma unroll
            for (int j = 0; j < 8; j++) v[j] = (bf16)0.f;
            if (lq < 2) {
                int col = n0 + wn * 32 + nt * 16 + lr;
#pragma unroll
                for (int j = 0; j < 8; j++)
                    v[j] = (bf16)bias[(size_t)(lq * 8 + j) * OUT_DIM + col];
            }
            bb[nt] = v;
        }
#pragma unroll
        for (int mt = 0; mt < 4; mt++)
#pragma unroll
            for (int nt = 0; nt < 2; nt++)
                acc[mt][nt] = __builtin_amdgcn_mfma_f32_16x16x32_bf16(
                    acw[mt], bb[nt], acc[mt][nt], 0, 0, 0);
    }

    // epilogue: relu + store (C/D: col = lane&15, row = quad*4 + reg)
#pragma unroll
    for (int mt = 0; mt < 4; mt++) {
        int row = m0 + wm * 64 + mt * 16 + lq * 4;
#pragma unroll
        for (int nt = 0; nt < 2; nt++) {
            int col = n0 + wn * 32 + nt * 16 + lr;
#pragma unroll
            for (int r2 = 0; r2 < 4; r2++) {
                float v = acc[mt][nt][r2];
                out[(size_t)(row + r2) * OUT_DIM + col] = v > 0.f ? v : 0.f;
            }
        }
    }
}

// ---------------------------------------------------------------------------
// Insurance fallback if ws_size is too small.
// ---------------------------------------------------------------------------
__global__ void fallback_kernel(const float* __restrict__ x, const float* __restrict__ cw,
                                const float* __restrict__ W, const float* __restrict__ bias,
                                float* __restrict__ out) {
    int o = blockIdx.x * 256 + threadIdx.x;
    int b = o >> 10, oc = o & 1023;
    const float* xr = x + (size_t)b * IN_DIM;
    float accv = 0.f;
    for (int n = 0; n < NEXP; n++) {
        const float* wr = W + (size_t)n * IN_DIM * OUT_DIM + oc;
        float z = 0.f;
        for (int i = 0; i < IN_DIM; i++) z += xr[i] * wr[(size_t)i * OUT_DIM];
        accv += cw[(size_t)b * NEXP + n] * (z + bias[n * OUT_DIM + oc]);
    }
    out[o] = accv > 0.f ? accv : 0.f;
}

extern "C" void kernel_launch(void* const* d_in, const int* in_sizes, int n_in,
                              void* d_out, int out_size, void* d_ws, size_t ws_size,
                              hipStream_t stream) {
    const float* x    = (const float*)d_in[0];
    const float* cw   = (const float*)d_in[1];
    const float* W    = (const float*)d_in[2];
    const float* bias = (const float*)d_in[3];
    float* out = (float*)d_out;

    const size_t wt_elems = (size_t)NEXP * IN_DIM * OUT_DIM;   // 32 MB bf16
    const size_t xt_elems = (size_t)BATCH * IN_DIM;            // 8 MB bf16
    if (ws_size < (wt_elems + xt_elems) * sizeof(bf16)) {
        fallback_kernel<<<(BATCH * OUT_DIM) / 256, 256, 0, stream>>>(x, cw, W, bias, out);
        return;
    }
    bf16* wt = (bf16*)d_ws;
    bf16* xt = wt + wt_elems;

    convert_all<<<4096 + 512, 256, 0, stream>>>(x, W, xt, wt);
    moe_gemm<<<dim3(16, 32), 256, 0, stream>>>(cw, bias, xt, wt, out);
}